// Round 10
// baseline (241.862 us; speedup 1.0000x reference)
//
#include <hip/hip_runtime.h>
#include <stdint.h>

#define EMB_DIM 192
#define CDIM 32
#define TDIM 4
#define N_Y 50000
#define N_X 32768
#define KNBR 8
#define ECNT (N_X*KNBR)  // 262144

// LDS row strides (shorts), odd-word -> low conflicts (proven R3-R5)
#define H1S 134
#define H2S 262
#define KS  33
#define ES  200

// prep_c block ranges: [0,782) Y rows, [782,1294) X rows
#define PREP_CY 782
#define PREP_CX 512
#define PREP_CNB (PREP_CY + PREP_CX)

// prep_w: w0t 49152 + w1t 32768 + w2t 32768 + w3t 4096 = 118784 elems
#define PREP_WNB 464

typedef __attribute__((ext_vector_type(8))) short bf16x8;
typedef __attribute__((ext_vector_type(4))) float f32x4;
typedef __attribute__((ext_vector_type(2))) float f32x2;

static __device__ __forceinline__ short f2bf(float f){
  unsigned u = __float_as_uint(f);
  return (short)((u + 0x7FFFu) >> 16);
}
static __device__ __forceinline__ unsigned pk_bf16(float lo, float hi){
  return ((__float_as_uint(lo) + 0x7FFFu) >> 16) |
         ((((__float_as_uint(hi) + 0x7FFFu) >> 16)) << 16);
}
// scalar gelu (exp2-fold, proven R6) — used by odd sites only
static __device__ __forceinline__ float geluf(float x){
  float x2 = x * x;
  float w  = __builtin_fmaf(x2, -0.10294324f, -2.3022082f);
  float e  = __builtin_amdgcn_exp2f(x * w);
  return x * __builtin_amdgcn_rcpf(1.0f + e);
}
// R10: paired gelu via <2 x float> — LLVM emits VOP3P v_pk_mul/add/fma_f32
// on gfx90a+ for ext-vector f32 arithmetic. 2 gelus: 5 pk + 4 trans issue
// slots (was 10 scalar + 4 trans). Per-element ops identical IEEE ->
// bit-identical results vs geluf.
static __device__ __forceinline__ f32x2 gelu2(f32x2 x){
  f32x2 x2 = x * x;                                   // v_pk_mul_f32
#if __has_builtin(__builtin_elementwise_fma)
  f32x2 w  = __builtin_elementwise_fma(
      x2, (f32x2){-0.10294324f, -0.10294324f},
          (f32x2){-2.3022082f, -2.3022082f});          // v_pk_fma_f32
#else
  f32x2 w; w.x = __builtin_fmaf(x2.x, -0.10294324f, -2.3022082f);
           w.y = __builtin_fmaf(x2.y, -0.10294324f, -2.3022082f);
#endif
  f32x2 arg = x * w;                                  // v_pk_mul_f32
  f32x2 e;
  e.x = __builtin_amdgcn_exp2f(arg.x);                // v_exp_f32
  e.y = __builtin_amdgcn_exp2f(arg.y);
  f32x2 d = e + (f32x2){1.0f, 1.0f};                  // v_pk_add_f32
  f32x2 r;
  r.x = __builtin_amdgcn_rcpf(d.x);                   // v_rcp_f32
  r.y = __builtin_amdgcn_rcpf(d.y);
  return x * r;                                       // v_pk_mul_f32
}

// ---- prep_w: ALL weight transposes to bf16 ----
__global__ __launch_bounds__(256) void prep_w(
    const float* __restrict__ W0, const float* __restrict__ W1,
    const float* __restrict__ W2, const float* __restrict__ W3,
    short* __restrict__ w0t, short* __restrict__ w1t,
    short* __restrict__ w2t, short* __restrict__ w3t)
{
  int id = blockIdx.x * 256 + threadIdx.x;
  if (id < 49152) {
    int k = id >> 7, n = id & 127;
    w0t[n * 384 + k] = f2bf(W0[(size_t)k * 128 + n]);
  } else if (id < 81920) {
    int loc = id - 49152; int n = loc >> 7, k = loc & 127;
    w1t[loc] = f2bf(W1[k * 256 + n]);
  } else if (id < 114688) {
    int loc = id - 81920; int n = loc >> 8, k = loc & 255;
    w2t[loc] = f2bf(W2[k * 128 + n]);
  } else if (id < 118784) {
    int loc = id - 114688; int n = loc >> 7, k = loc & 127;
    w3t[loc] = f2bf(W3[k * 32 + n]);
  }
}

// ---- prep_c: embed + layer0 GEMM (unchanged) ----
__global__ __launch_bounds__(256, 2) void prep_c(
    const float* __restrict__ ypts, const float* __restrict__ xpts,
    const short* __restrict__ w0t, const float* __restrict__ b0,
    short* __restrict__ c_y, float* __restrict__ c_x)
{
  __shared__ __attribute__((aligned(16))) short s_e[64 * ES];
  const int tid = threadIdx.x;
  const bool isY = blockIdx.x < PREP_CY;
  const int row0 = isY ? blockIdx.x * 64 : (blockIdx.x - PREP_CY) * 64;
  const int wave = tid >> 6, lane = tid & 63;
  const int quad = lane >> 4, l15 = lane & 15;
  const short* w0h = w0t + (isY ? 0 : 192);

  bf16x8 bv[2][6];
  #pragma unroll
  for (int nt = 0; nt < 2; ++nt) {
    int n = wave * 32 + nt * 16 + l15;
    #pragma unroll
    for (int ch = 0; ch < 6; ++ch)
      bv[nt][ch] = *(const bf16x8*)&w0h[(size_t)n * 384 + ch * 32 + quad * 8];
  }

  {
    const int r = tid >> 2, q = tid & 3;
    const int grow = row0 + r;
    const bool valid = isY ? (grow < N_Y) : true;
    const float* src = isY ? (ypts + (size_t)grow * 3) : (xpts + (size_t)grow * 3);
    float c[3] = {0.f, 0.f, 0.f};
    if (valid) { c[0] = src[0]; c[1] = src[1]; c[2] = src[2]; }
    #pragma unroll
    for (int j = 0; j < 24; ++j) {
      int p = q * 24 + j;
      int d = p >> 5, i = p & 31;
      float f = __expf(-0.28782313662425575f * (float)i);
      float rev = c[d] * f * 0.15915494309189535f;
      float s  = __builtin_amdgcn_sinf(rev);
      float co = __builtin_amdgcn_cosf(rev);
      *(unsigned*)&s_e[r * ES + d * 64 + 2 * i] = pk_bf16(s, co);
    }
  }
  __syncthreads();

  f32x4 acc[4][2];
  #pragma unroll
  for (int mt = 0; mt < 4; ++mt)
    #pragma unroll
    for (int nt = 0; nt < 2; ++nt) acc[mt][nt] = (f32x4){0.f, 0.f, 0.f, 0.f};
  #pragma unroll
  for (int ch = 0; ch < 6; ++ch) {
    bf16x8 a[4];
    #pragma unroll
    for (int mt = 0; mt < 4; ++mt)
      a[mt] = *(const bf16x8*)&s_e[(mt * 16 + l15) * ES + ch * 32 + quad * 8];
    #pragma unroll
    for (int mt = 0; mt < 4; ++mt)
      #pragma unroll
      for (int nt = 0; nt < 2; ++nt)
        acc[mt][nt] = __builtin_amdgcn_mfma_f32_16x16x32_bf16(
            a[mt], bv[nt][ch], acc[mt][nt], 0, 0, 0);
  }
  #pragma unroll
  for (int nt = 0; nt < 2; ++nt) {
    int col = wave * 32 + nt * 16 + l15;
    float bias = isY ? 0.f : b0[col];
    #pragma unroll
    for (int mt = 0; mt < 4; ++mt)
      #pragma unroll
      for (int rg = 0; rg < 4; ++rg) {
        int grow = row0 + mt * 16 + quad * 4 + rg;
        if (isY) { if (grow < N_Y) c_y[(size_t)grow * 128 + col] = f2bf(acc[mt][nt][rg]); }
        else     { c_x[(size_t)grow * 128 + col] = acc[mt][nt][rg] + bias; }
      }
  }
}

// ---- edge kernel: R6 structure + R10 packed-f32 gelu pairs ----
// Block-shared weights + 4-barrier chain are load-bearing (R8). Latency-
// bound at ~46% issue duty; VALU-work is the proven lever (R6, ~0.7:1).
// R10 packs gelu+bias math into v_pk_* VOP3P pairs: -25% VALU issue slots,
// bit-identical results.
// region1 [0,33536): h2 (64xH2S bf16), later kern (64xKS f32)
// region2 [33536,50688): h1 (64xH1S bf16), later h3
__global__ __launch_bounds__(256, 3) void fused_edge(
    const short* __restrict__ c_y, const float* __restrict__ c_x,
    const int* __restrict__ nidx, const float* __restrict__ f_y,
    const short* __restrict__ w1t, const float* __restrict__ b1,
    const short* __restrict__ w2t, const float* __restrict__ b2,
    const short* __restrict__ w3t, const float* __restrict__ b3,
    float* __restrict__ out)
{
  __shared__ __attribute__((aligned(16))) char smem[50688];
  __shared__ int s_nidx[64];
  short* s_h2   = (short*)smem;
  float* s_kern = (float*)smem;
  short* s_h1   = (short*)(smem + 33536);

  const int tid  = threadIdx.x;
  const int e0   = blockIdx.x * 64;
  const int wave = tid >> 6, lane = tid & 63;
  const int quad = lane >> 4, l15 = lane & 15;
  const int xloc = tid >> 5, cc = tid & 31;

  // ---- phase 0: h1 = gelu(c_y[idx] + c_x[e>>3]) ----
  {
    const int r = tid >> 2, q = tid & 3;
    const int idx = nidx[e0 + r];
    if (q == 0) s_nidx[r] = idx;
    const uint4*  cyp = (const uint4*)(c_y + (size_t)idx * 128 + q * 32);
    const float4* cxp = (const float4*)(c_x + (size_t)((e0 + r) >> 3) * 128 + q * 32);
    uint4  cyv[4];
    float4 cxv[8];
    #pragma unroll
    for (int i = 0; i < 4; ++i) cyv[i] = cyp[i];
    #pragma unroll
    for (int i = 0; i < 8; ++i) cxv[i] = cxp[i];
    const float* cxa = (const float*)cxv;
    const unsigned* cya = (const unsigned*)cyv;
    unsigned pk[16];
    #pragma unroll
    for (int jj = 0; jj < 16; ++jj) {
      unsigned u = cya[jj];
      f32x2 v;
      v.x = __uint_as_float(u << 16);
      v.y = __uint_as_float(u & 0xffff0000u);
      v = v + (f32x2){cxa[2 * jj], cxa[2 * jj + 1]};   // v_pk_add_f32
      f32x2 gld = gelu2(v);
      pk[jj] = pk_bf16(gld.x, gld.y);
    }
    uint4* dst = (uint4*)&s_h1[r * H1S + q * 32];
    #pragma unroll
    for (int jj = 0; jj < 4; ++jj)
      dst[jj] = *(uint4*)&pk[jj * 4];
  }
  __syncthreads();

  // ---- early f_y gather: idx from LDS; latency hides under L1; pinned ----
  float fv[KNBR][TDIM];
  #pragma unroll
  for (int j = 0; j < KNBR; ++j) {
    int idxj = s_nidx[xloc * 8 + j];
    const float* fp = f_y + (size_t)idxj * CDIM + cc;
    #pragma unroll
    for (int t = 0; t < TDIM; ++t)
      fv[j][t] = fp[(size_t)t * (N_Y * CDIM)];
  }

  // ---------- layer 1: 128 -> 256, GELU (wave owns 64 cols) ----------
  {
    f32x4 acc1[4][4];
    #pragma unroll
    for (int mt = 0; mt < 4; ++mt)
      #pragma unroll
      for (int nt = 0; nt < 4; ++nt) acc1[mt][nt] = (f32x4){0.f, 0.f, 0.f, 0.f};
    #pragma unroll
    for (int ch = 0; ch < 4; ++ch) {
      bf16x8 a[4], b[4];
      #pragma unroll
      for (int mt = 0; mt < 4; ++mt)
        a[mt] = *(const bf16x8*)&s_h1[(mt * 16 + l15) * H1S + ch * 32 + quad * 8];
      #pragma unroll
      for (int nt = 0; nt < 4; ++nt)
        b[nt] = *(const bf16x8*)&w1t[(size_t)(wave * 64 + nt * 16 + l15) * 128 + ch * 32 + quad * 8];
      #pragma unroll
      for (int mt = 0; mt < 4; ++mt)
        #pragma unroll
        for (int nt = 0; nt < 4; ++nt)
          acc1[mt][nt] = __builtin_amdgcn_mfma_f32_16x16x32_bf16(a[mt], b[nt], acc1[mt][nt], 0, 0, 0);
    }
    #pragma unroll
    for (int nt = 0; nt < 4; ++nt) {
      int col = wave * 64 + nt * 16 + l15;
      float bias = b1[col];
      f32x2 bb2 = {bias, bias};
      #pragma unroll
      for (int mt = 0; mt < 4; ++mt) {
        int row0r = mt * 16 + quad * 4;
        f32x2 g01 = gelu2((f32x2){acc1[mt][nt][0], acc1[mt][nt][1]} + bb2);
        f32x2 g23 = gelu2((f32x2){acc1[mt][nt][2], acc1[mt][nt][3]} + bb2);
        s_h2[(row0r + 0) * H2S + col] = f2bf(g01.x);
        s_h2[(row0r + 1) * H2S + col] = f2bf(g01.y);
        s_h2[(row0r + 2) * H2S + col] = f2bf(g23.x);
        s_h2[(row0r + 3) * H2S + col] = f2bf(g23.y);
      }
    }
  }
  // pin the early gather results: loads must issue before this point
  #pragma unroll
  for (int j = 0; j < KNBR; ++j)
    #pragma unroll
    for (int t = 0; t < TDIM; ++t)
      asm volatile("" :: "v"(fv[j][t]));
  __syncthreads();   // h2 visible; h1 reads done -> h3 may overwrite region2

  // ---------- layer 2: 256 -> 128, GELU (wave owns 32 cols) ----------
  {
    f32x4 acc2[4][2];
    #pragma unroll
    for (int mt = 0; mt < 4; ++mt)
      #pragma unroll
      for (int nt = 0; nt < 2; ++nt) acc2[mt][nt] = (f32x4){0.f, 0.f, 0.f, 0.f};
    #pragma unroll
    for (int ch = 0; ch < 8; ++ch) {
      bf16x8 a[4], b[2];
      #pragma unroll
      for (int mt = 0; mt < 4; ++mt)
        a[mt] = *(const bf16x8*)&s_h2[(mt * 16 + l15) * H2S + ch * 32 + quad * 8];
      #pragma unroll
      for (int nt = 0; nt < 2; ++nt)
        b[nt] = *(const bf16x8*)&w2t[(size_t)(wave * 32 + nt * 16 + l15) * 256 + ch * 32 + quad * 8];
      #pragma unroll
      for (int mt = 0; mt < 4; ++mt)
        #pragma unroll
        for (int nt = 0; nt < 2; ++nt)
          acc2[mt][nt] = __builtin_amdgcn_mfma_f32_16x16x32_bf16(a[mt], b[nt], acc2[mt][nt], 0, 0, 0);
    }
    #pragma unroll
    for (int nt = 0; nt < 2; ++nt) {
      int col = wave * 32 + nt * 16 + l15;
      float bias = b2[col];
      f32x2 bb2 = {bias, bias};
      #pragma unroll
      for (int mt = 0; mt < 4; ++mt) {
        int row0r = mt * 16 + quad * 4;
        f32x2 g01 = gelu2((f32x2){acc2[mt][nt][0], acc2[mt][nt][1]} + bb2);
        f32x2 g23 = gelu2((f32x2){acc2[mt][nt][2], acc2[mt][nt][3]} + bb2);
        s_h1[(row0r + 0) * H1S + col] = f2bf(g01.x);   // h3
        s_h1[(row0r + 1) * H1S + col] = f2bf(g01.y);
        s_h1[(row0r + 2) * H1S + col] = f2bf(g23.x);
        s_h1[(row0r + 3) * H1S + col] = f2bf(g23.y);
      }
    }
  }
  __syncthreads();   // h3 visible; h2 reads done -> kern may overwrite region1

  // ---------- layer 3: 128 -> 32 linear (wave owns 16 rows) -> s_kern ----------
  {
    f32x4 acc3[2];
    acc3[0] = (f32x4){0.f, 0.f, 0.f, 0.f};
    acc3[1] = (f32x4){0.f, 0.f, 0.f, 0.f};
    #pragma unroll
    for (int ch = 0; ch < 4; ++ch) {
      bf16x8 a3 = *(const bf16x8*)&s_h1[(wave * 16 + l15) * H1S + ch * 32 + quad * 8];
      #pragma unroll
      for (int nt = 0; nt < 2; ++nt) {
        bf16x8 b3f = *(const bf16x8*)&w3t[(size_t)(nt * 16 + l15) * 128 + ch * 32 + quad * 8];
        acc3[nt] = __builtin_amdgcn_mfma_f32_16x16x32_bf16(a3, b3f, acc3[nt], 0, 0, 0);
      }
    }
    #pragma unroll
    for (int nt = 0; nt < 2; ++nt) {
      int col = nt * 16 + l15;
      float bias = b3[col];
      #pragma unroll
      for (int rg = 0; rg < 4; ++rg) {
        int row = wave * 16 + quad * 4 + rg;
        s_kern[row * KS + col] = acc3[nt][rg] + bias;
      }
    }
  }
  __syncthreads();

  // ---------- fused reduce: LDS kern + prefetched fv registers ----------
  {
    float acc[TDIM] = {0.f, 0.f, 0.f, 0.f};
    const int ebase = xloc * 8;
    #pragma unroll
    for (int j = 0; j < KNBR; ++j) {
      float kv = s_kern[(ebase + j) * KS + cc];
      #pragma unroll
      for (int t = 0; t < TDIM; ++t)
        acc[t] += kv * fv[j][t];
    }
    const int xg = blockIdx.x * 8 + xloc;
    #pragma unroll
    for (int t = 0; t < TDIM; ++t)
      out[((size_t)t * N_X + xg) * CDIM + cc] = acc[t];
  }
}

extern "C" void kernel_launch(void* const* d_in, const int* in_sizes, int n_in,
                              void* d_out, int out_size, void* d_ws, size_t ws_size,
                              hipStream_t stream)
{
  const float* y   = (const float*)d_in[0];
  const float* x   = (const float*)d_in[1];
  const float* f_y = (const float*)d_in[2];
  const int*  nidx = (const int*)d_in[3];
  const float* W0 = (const float*)d_in[4];  const float* b0 = (const float*)d_in[5];
  const float* W1 = (const float*)d_in[6];  const float* b1 = (const float*)d_in[7];
  const float* W2 = (const float*)d_in[8];  const float* b2 = (const float*)d_in[9];
  const float* W3 = (const float*)d_in[10]; const float* b3 = (const float*)d_in[11];

  char* ws = (char*)d_ws;
  short* c_y  = (short*)(ws + 0);           // 50000*128*2  = 12,800,000
  float* c_x  = (float*)(ws + 12800000);    // 32768*128*4  = 16,777,216
  short* w1t  = (short*)(ws + 29577216);    // 256*128*2    = 65,536
  short* w2t  = (short*)(ws + 29642752);    // 128*256*2    = 65,536
  short* w3t  = (short*)(ws + 29708288);    //  32*128*2    = 8,192
  short* w0t  = (short*)(ws + 29716480);    // 128*384*2    = 98,304

  hipLaunchKernelGGL(prep_w, dim3(PREP_WNB), dim3(256), 0, stream,
                     W0, W1, W2, W3, w0t, w1t, w2t, w3t);
  hipLaunchKernelGGL(prep_c, dim3(PREP_CNB), dim3(256), 0, stream,
                     y, x, w0t, b0, c_y, c_x);
  hipLaunchKernelGGL(fused_edge, dim3(ECNT / 64), dim3(256), 0, stream,
                     c_y, c_x, nidx, f_y, w1t, b1, w2t, b2, w3t, b3, (float*)d_out);
}

// Round 11
// 236.317 us; speedup vs baseline: 1.0235x; 1.0235x over previous
//
#include <hip/hip_runtime.h>
#include <stdint.h>

#define EMB_DIM 192
#define CDIM 32
#define TDIM 4
#define N_Y 50000
#define N_X 32768
#define KNBR 8
#define ECNT (N_X*KNBR)  // 262144

// LDS row strides (shorts), odd-word -> low conflicts (proven R3-R5)
#define H1S 134
#define H2S 262
#define KS  33
#define ES  200

// prep_c block ranges: [0,782) Y rows, [782,1294) X rows
#define PREP_CY 782
#define PREP_CX 512
#define PREP_CNB (PREP_CY + PREP_CX)

// prep_w: w0t 49152 + w1t 32768 + w2t 32768 + w3t 4096 = 118784 elems
#define PREP_WNB 464

typedef __attribute__((ext_vector_type(8))) short bf16x8;
typedef __attribute__((ext_vector_type(4))) float f32x4;

static __device__ __forceinline__ short f2bf(float f){
  unsigned u = __float_as_uint(f);
  return (short)((u + 0x7FFFu) >> 16);
}
static __device__ __forceinline__ unsigned pk_bf16(float lo, float hi){
  return ((__float_as_uint(lo) + 0x7FFFu) >> 16) |
         ((((__float_as_uint(hi) + 0x7FFFu) >> 16)) << 16);
}
// gelu via exp2-fold (proven R6): arg = x*(c0 + c1*x^2), log2(e) absorbed into
// c0 = -2*0.7978845608*log2e, c1 = c0*0.044715. Shortens the dependency
// chain by 2 serial muls vs the __expf form — the only lever that moved
// time 1:1 in this latency-bound kernel (R6 vs R10 evidence).
static __device__ __forceinline__ float geluf(float x){
  float x2 = x * x;
  float w  = __builtin_fmaf(x2, -0.10294324f, -2.3022082f);
  float e  = __builtin_amdgcn_exp2f(x * w);   // v_exp_f32
  return x * __builtin_amdgcn_rcpf(1.0f + e);
}

// ---- prep_w: ALL weight transposes to bf16 ----
__global__ __launch_bounds__(256) void prep_w(
    const float* __restrict__ W0, const float* __restrict__ W1,
    const float* __restrict__ W2, const float* __restrict__ W3,
    short* __restrict__ w0t, short* __restrict__ w1t,
    short* __restrict__ w2t, short* __restrict__ w3t)
{
  int id = blockIdx.x * 256 + threadIdx.x;
  if (id < 49152) {
    int k = id >> 7, n = id & 127;
    w0t[n * 384 + k] = f2bf(W0[(size_t)k * 128 + n]);
  } else if (id < 81920) {
    int loc = id - 49152; int n = loc >> 7, k = loc & 127;
    w1t[loc] = f2bf(W1[k * 256 + n]);
  } else if (id < 114688) {
    int loc = id - 81920; int n = loc >> 8, k = loc & 255;
    w2t[loc] = f2bf(W2[k * 128 + n]);
  } else if (id < 118784) {
    int loc = id - 114688; int n = loc >> 7, k = loc & 127;
    w3t[loc] = f2bf(W3[k * 32 + n]);
  }
}

// ---- prep_c: embed + layer0 GEMM ----
__global__ __launch_bounds__(256, 2) void prep_c(
    const float* __restrict__ ypts, const float* __restrict__ xpts,
    const short* __restrict__ w0t, const float* __restrict__ b0,
    short* __restrict__ c_y, float* __restrict__ c_x)
{
  __shared__ __attribute__((aligned(16))) short s_e[64 * ES];
  const int tid = threadIdx.x;
  const bool isY = blockIdx.x < PREP_CY;
  const int row0 = isY ? blockIdx.x * 64 : (blockIdx.x - PREP_CY) * 64;
  const int wave = tid >> 6, lane = tid & 63;
  const int quad = lane >> 4, l15 = lane & 15;
  const short* w0h = w0t + (isY ? 0 : 192);

  bf16x8 bv[2][6];
  #pragma unroll
  for (int nt = 0; nt < 2; ++nt) {
    int n = wave * 32 + nt * 16 + l15;
    #pragma unroll
    for (int ch = 0; ch < 6; ++ch)
      bv[nt][ch] = *(const bf16x8*)&w0h[(size_t)n * 384 + ch * 32 + quad * 8];
  }

  {
    const int r = tid >> 2, q = tid & 3;
    const int grow = row0 + r;
    const bool valid = isY ? (grow < N_Y) : true;
    const float* src = isY ? (ypts + (size_t)grow * 3) : (xpts + (size_t)grow * 3);
    float c[3] = {0.f, 0.f, 0.f};
    if (valid) { c[0] = src[0]; c[1] = src[1]; c[2] = src[2]; }
    #pragma unroll
    for (int j = 0; j < 24; ++j) {
      int p = q * 24 + j;
      int d = p >> 5, i = p & 31;
      float f = __expf(-0.28782313662425575f * (float)i);
      float rev = c[d] * f * 0.15915494309189535f;
      float s  = __builtin_amdgcn_sinf(rev);
      float co = __builtin_amdgcn_cosf(rev);
      *(unsigned*)&s_e[r * ES + d * 64 + 2 * i] = pk_bf16(s, co);
    }
  }
  __syncthreads();

  f32x4 acc[4][2];
  #pragma unroll
  for (int mt = 0; mt < 4; ++mt)
    #pragma unroll
    for (int nt = 0; nt < 2; ++nt) acc[mt][nt] = (f32x4){0.f, 0.f, 0.f, 0.f};
  #pragma unroll
  for (int ch = 0; ch < 6; ++ch) {
    bf16x8 a[4];
    #pragma unroll
    for (int mt = 0; mt < 4; ++mt)
      a[mt] = *(const bf16x8*)&s_e[(mt * 16 + l15) * ES + ch * 32 + quad * 8];
    #pragma unroll
    for (int mt = 0; mt < 4; ++mt)
      #pragma unroll
      for (int nt = 0; nt < 2; ++nt)
        acc[mt][nt] = __builtin_amdgcn_mfma_f32_16x16x32_bf16(
            a[mt], bv[nt][ch], acc[mt][nt], 0, 0, 0);
  }
  #pragma unroll
  for (int nt = 0; nt < 2; ++nt) {
    int col = wave * 32 + nt * 16 + l15;
    float bias = isY ? 0.f : b0[col];
    #pragma unroll
    for (int mt = 0; mt < 4; ++mt)
      #pragma unroll
      for (int rg = 0; rg < 4; ++rg) {
        int grow = row0 + mt * 16 + quad * 4 + rg;
        if (isY) { if (grow < N_Y) c_y[(size_t)grow * 128 + col] = f2bf(acc[mt][nt][rg]); }
        else     { c_x[(size_t)grow * 128 + col] = acc[mt][nt][rg] + bias; }
      }
  }
}

// ---- edge kernel: proven optimum (141us, reproduced R6/R9) — FINAL ----
// Structural constraints, all measured:
//  * block-shared weight B-frags + 4-barrier chain are load-bearing
//    (R8: wave-private/zero-barrier variant 2x slower)
//  * 3 blocks/CU x 4 waves is the best occupancy point (R2/R4 regressed)
//  * latency-bound: issue-slot cuts don't help (R10), chain cuts do (R6)
//  * remaining stall is L3-gather + LDS->MFMA chain latency, correlated
//    by barriers — no tested configuration reduces it further.
// region1 [0,33536): h2 (64xH2S bf16), later kern (64xKS f32)
// region2 [33536,50688): h1 (64xH1S bf16), later h3
__global__ __launch_bounds__(256, 3) void fused_edge(
    const short* __restrict__ c_y, const float* __restrict__ c_x,
    const int* __restrict__ nidx, const float* __restrict__ f_y,
    const short* __restrict__ w1t, const float* __restrict__ b1,
    const short* __restrict__ w2t, const float* __restrict__ b2,
    const short* __restrict__ w3t, const float* __restrict__ b3,
    float* __restrict__ out)
{
  __shared__ __attribute__((aligned(16))) char smem[50688];
  __shared__ int s_nidx[64];
  short* s_h2   = (short*)smem;
  float* s_kern = (float*)smem;
  short* s_h1   = (short*)(smem + 33536);

  const int tid  = threadIdx.x;
  const int e0   = blockIdx.x * 64;
  const int wave = tid >> 6, lane = tid & 63;
  const int quad = lane >> 4, l15 = lane & 15;
  const int xloc = tid >> 5, cc = tid & 31;

  // ---- phase 0: h1 = gelu(c_y[idx] + c_x[e>>3]) ----
  {
    const int r = tid >> 2, q = tid & 3;
    const int idx = nidx[e0 + r];
    if (q == 0) s_nidx[r] = idx;
    const uint4*  cyp = (const uint4*)(c_y + (size_t)idx * 128 + q * 32);
    const float4* cxp = (const float4*)(c_x + (size_t)((e0 + r) >> 3) * 128 + q * 32);
    uint4  cyv[4];
    float4 cxv[8];
    #pragma unroll
    for (int i = 0; i < 4; ++i) cyv[i] = cyp[i];
    #pragma unroll
    for (int i = 0; i < 8; ++i) cxv[i] = cxp[i];
    const float* cxa = (const float*)cxv;
    const unsigned* cya = (const unsigned*)cyv;
    unsigned pk[16];
    #pragma unroll
    for (int jj = 0; jj < 16; ++jj) {
      unsigned u = cya[jj];
      float lo = __uint_as_float(u << 16)         + cxa[2 * jj];
      float hi = __uint_as_float(u & 0xffff0000u) + cxa[2 * jj + 1];
      pk[jj] = pk_bf16(geluf(lo), geluf(hi));
    }
    uint4* dst = (uint4*)&s_h1[r * H1S + q * 32];
    #pragma unroll
    for (int jj = 0; jj < 4; ++jj)
      dst[jj] = *(uint4*)&pk[jj * 4];
  }
  __syncthreads();

  // ---- early f_y gather: idx from LDS; latency hides under L1; pinned ----
  float fv[KNBR][TDIM];
  #pragma unroll
  for (int j = 0; j < KNBR; ++j) {
    int idxj = s_nidx[xloc * 8 + j];
    const float* fp = f_y + (size_t)idxj * CDIM + cc;
    #pragma unroll
    for (int t = 0; t < TDIM; ++t)
      fv[j][t] = fp[(size_t)t * (N_Y * CDIM)];
  }

  // ---------- layer 1: 128 -> 256, GELU (wave owns 64 cols) ----------
  {
    f32x4 acc1[4][4];
    #pragma unroll
    for (int mt = 0; mt < 4; ++mt)
      #pragma unroll
      for (int nt = 0; nt < 4; ++nt) acc1[mt][nt] = (f32x4){0.f, 0.f, 0.f, 0.f};
    #pragma unroll
    for (int ch = 0; ch < 4; ++ch) {
      bf16x8 a[4], b[4];
      #pragma unroll
      for (int mt = 0; mt < 4; ++mt)
        a[mt] = *(const bf16x8*)&s_h1[(mt * 16 + l15) * H1S + ch * 32 + quad * 8];
      #pragma unroll
      for (int nt = 0; nt < 4; ++nt)
        b[nt] = *(const bf16x8*)&w1t[(size_t)(wave * 64 + nt * 16 + l15) * 128 + ch * 32 + quad * 8];
      #pragma unroll
      for (int mt = 0; mt < 4; ++mt)
        #pragma unroll
        for (int nt = 0; nt < 4; ++nt)
          acc1[mt][nt] = __builtin_amdgcn_mfma_f32_16x16x32_bf16(a[mt], b[nt], acc1[mt][nt], 0, 0, 0);
    }
    #pragma unroll
    for (int nt = 0; nt < 4; ++nt) {
      int col = wave * 64 + nt * 16 + l15;
      float bias = b1[col];
      #pragma unroll
      for (int mt = 0; mt < 4; ++mt)
        #pragma unroll
        for (int rg = 0; rg < 4; ++rg) {
          int row = mt * 16 + quad * 4 + rg;
          s_h2[row * H2S + col] = f2bf(geluf(acc1[mt][nt][rg] + bias));
        }
    }
  }
  // pin the early gather results: loads must issue before this point
  #pragma unroll
  for (int j = 0; j < KNBR; ++j)
    #pragma unroll
    for (int t = 0; t < TDIM; ++t)
      asm volatile("" :: "v"(fv[j][t]));
  __syncthreads();   // h2 visible; h1 reads done -> h3 may overwrite region2

  // ---------- layer 2: 256 -> 128, GELU (wave owns 32 cols) ----------
  {
    f32x4 acc2[4][2];
    #pragma unroll
    for (int mt = 0; mt < 4; ++mt)
      #pragma unroll
      for (int nt = 0; nt < 2; ++nt) acc2[mt][nt] = (f32x4){0.f, 0.f, 0.f, 0.f};
    #pragma unroll
    for (int ch = 0; ch < 8; ++ch) {
      bf16x8 a[4], b[2];
      #pragma unroll
      for (int mt = 0; mt < 4; ++mt)
        a[mt] = *(const bf16x8*)&s_h2[(mt * 16 + l15) * H2S + ch * 32 + quad * 8];
      #pragma unroll
      for (int nt = 0; nt < 2; ++nt)
        b[nt] = *(const bf16x8*)&w2t[(size_t)(wave * 32 + nt * 16 + l15) * 256 + ch * 32 + quad * 8];
      #pragma unroll
      for (int mt = 0; mt < 4; ++mt)
        #pragma unroll
        for (int nt = 0; nt < 2; ++nt)
          acc2[mt][nt] = __builtin_amdgcn_mfma_f32_16x16x32_bf16(a[mt], b[nt], acc2[mt][nt], 0, 0, 0);
    }
    #pragma unroll
    for (int nt = 0; nt < 2; ++nt) {
      int col = wave * 32 + nt * 16 + l15;
      float bias = b2[col];
      #pragma unroll
      for (int mt = 0; mt < 4; ++mt)
        #pragma unroll
        for (int rg = 0; rg < 4; ++rg) {
          int row = mt * 16 + quad * 4 + rg;
          s_h1[row * H1S + col] = f2bf(geluf(acc2[mt][nt][rg] + bias));   // h3
        }
    }
  }
  __syncthreads();   // h3 visible; h2 reads done -> kern may overwrite region1

  // ---------- layer 3: 128 -> 32 linear (wave owns 16 rows) -> s_kern ----------
  {
    f32x4 acc3[2];
    acc3[0] = (f32x4){0.f, 0.f, 0.f, 0.f};
    acc3[1] = (f32x4){0.f, 0.f, 0.f, 0.f};
    #pragma unroll
    for (int ch = 0; ch < 4; ++ch) {
      bf16x8 a3 = *(const bf16x8*)&s_h1[(wave * 16 + l15) * H1S + ch * 32 + quad * 8];
      #pragma unroll
      for (int nt = 0; nt < 2; ++nt) {
        bf16x8 b3f = *(const bf16x8*)&w3t[(size_t)(nt * 16 + l15) * 128 + ch * 32 + quad * 8];
        acc3[nt] = __builtin_amdgcn_mfma_f32_16x16x32_bf16(a3, b3f, acc3[nt], 0, 0, 0);
      }
    }
    #pragma unroll
    for (int nt = 0; nt < 2; ++nt) {
      int col = nt * 16 + l15;
      float bias = b3[col];
      #pragma unroll
      for (int rg = 0; rg < 4; ++rg) {
        int row = wave * 16 + quad * 4 + rg;
        s_kern[row * KS + col] = acc3[nt][rg] + bias;
      }
    }
  }
  __syncthreads();

  // ---------- fused reduce: LDS kern + prefetched fv registers ----------
  {
    float acc[TDIM] = {0.f, 0.f, 0.f, 0.f};
    const int ebase = xloc * 8;
    #pragma unroll
    for (int j = 0; j < KNBR; ++j) {
      float kv = s_kern[(ebase + j) * KS + cc];
      #pragma unroll
      for (int t = 0; t < TDIM; ++t)
        acc[t] += kv * fv[j][t];
    }
    const int xg = blockIdx.x * 8 + xloc;
    #pragma unroll
    for (int t = 0; t < TDIM; ++t)
      out[((size_t)t * N_X + xg) * CDIM + cc] = acc[t];
  }
}

extern "C" void kernel_launch(void* const* d_in, const int* in_sizes, int n_in,
                              void* d_out, int out_size, void* d_ws, size_t ws_size,
                              hipStream_t stream)
{
  const float* y   = (const float*)d_in[0];
  const float* x   = (const float*)d_in[1];
  const float* f_y = (const float*)d_in[2];
  const int*  nidx = (const int*)d_in[3];
  const float* W0 = (const float*)d_in[4];  const float* b0 = (const float*)d_in[5];
  const float* W1 = (const float*)d_in[6];  const float* b1 = (const float*)d_in[7];
  const float* W2 = (const float*)d_in[8];  const float* b2 = (const float*)d_in[9];
  const float* W3 = (const float*)d_in[10]; const float* b3 = (const float*)d_in[11];

  char* ws = (char*)d_ws;
  short* c_y  = (short*)(ws + 0);           // 50000*128*2  = 12,800,000
  float* c_x  = (float*)(ws + 12800000);    // 32768*128*4  = 16,777,216
  short* w1t  = (short*)(ws + 29577216);    // 256*128*2    = 65,536
  short* w2t  = (short*)(ws + 29642752);    // 128*256*2    = 65,536
  short* w3t  = (short*)(ws + 29708288);    //  32*128*2    = 8,192
  short* w0t  = (short*)(ws + 29716480);    // 128*384*2    = 98,304

  hipLaunchKernelGGL(prep_w, dim3(PREP_WNB), dim3(256), 0, stream,
                     W0, W1, W2, W3, w0t, w1t, w2t, w3t);
  hipLaunchKernelGGL(prep_c, dim3(PREP_CNB), dim3(256), 0, stream,
                     y, x, w0t, b0, c_y, c_x);
  hipLaunchKernelGGL(fused_edge, dim3(ECNT / 64), dim3(256), 0, stream,
                     c_y, c_x, nidx, f_y, w1t, b1, w2t, b2, w3t, b3, (float*)d_out);
}